// Round 7
// baseline (419.408 us; speedup 1.0000x reference)
//
#include <hip/hip_runtime.h>
#include <hip/hip_bf16.h>

typedef unsigned short u16;
typedef unsigned int u32;
typedef __attribute__((ext_vector_type(8))) short short8;
typedef __attribute__((ext_vector_type(4))) float floatx4;

#define N_PTS 16384
#define N_GRID 4096
#define GPTS 512
#define HD 128
#define DEG 16
#define QB 16
#define EB 256
#define EBLK (N_PTS / QB)    // 1024 edge blocks (512 threads, 16 queries each)
#define GABLK (N_GRID / 16)  // 256 ga blocks for standalone k_ga
#define GABLK2 (N_GRID / 32) // 128 ga rider blocks (2 tiles per 512-thread block)

// fast silu: v_rcp_f32 instead of full-precision divide (rel err ~2^-22)
__device__ __forceinline__ float silu_f(float x) {
    return x * __builtin_amdgcn_rcpf(1.0f + __expf(-x));
}
__device__ __forceinline__ short f2bf(float x) { return (short)__bfloat16_as_ushort(__float2bfloat16(x)); }

__global__ void k_fillf(float* out, float v, int n) {
    int i = blockIdx.x * blockDim.x + threadIdx.x;
    if (i < n) out[i] = v;
}

__global__ void k_init(const float* __restrict__ qp, const float* __restrict__ codes,
                       float* __restrict__ x_q, float* __restrict__ h_g, float* __restrict__ h_q,
                       float* __restrict__ Bq) {
    int stride = gridDim.x * blockDim.x;
    int i0 = blockIdx.x * blockDim.x + threadIdx.x;
    for (int i = i0; i < N_PTS * 3; i += stride) x_q[i] = qp[i];
    for (int i = i0; i < N_GRID * HD; i += stride) h_g[i] = codes[i];
    for (int i = i0; i < N_PTS * HD; i += stride) { h_q[i] = 0.0f; Bq[i] = 0.0f; }
}

// transpose We2 -> bf16 wsT[layer][f*128+k]
__global__ void k_prep(const float* __restrict__ eW2, short* __restrict__ wsT) {
    int idx = blockIdx.x * blockDim.x + threadIdx.x;
    if (idx >= 4 * HD * HD) return;
    int l = idx >> 14, rem = idx & 16383, f = rem >> 7, k = rem & 127;
    wsT[idx] = f2bf(eW2[l * 16384 + k * HD + f]);
}

// bf16 transposes for node MLP: nW1T[3][f*256+k], nW2T[3][f*128+k], W1midT[3][f*128+k]
__global__ void k_prep2(const float* __restrict__ nW1, const float* __restrict__ nW2,
                        const float* __restrict__ eW1,
                        short* __restrict__ nW1T, short* __restrict__ nW2T,
                        short* __restrict__ W1midT) {
    int idx = blockIdx.x * blockDim.x + threadIdx.x;
    if (idx < 3 * 32768) {
        int l = idx >> 15, r = idx & 32767, f = r >> 8, k = r & 255;
        nW1T[idx] = f2bf(nW1[l * 32768 + k * 128 + f]);
    } else if (idx < 3 * 32768 + 3 * 16384) {
        int j = idx - 3 * 32768;
        int l = j >> 14, r = j & 16383, f = r >> 7, k = r & 127;
        nW2T[j] = f2bf(nW2[l * 16384 + k * 128 + f]);
    } else if (idx < 3 * 32768 + 6 * 16384) {
        int j = idx - 3 * 32768 - 3 * 16384;
        int p = j >> 14, r = j & 16383, f = r >> 7, k = r & 127;
        W1midT[j] = f2bf(eW1[(p + 1) * 257 * 128 + (128 + k) * 128 + f]);
    }
}

// ---------------- ga body: 16 nodes per 256-thread group ----------------
__device__ __forceinline__ void ga_body(
    float* T1, float* T2, int n0, int tid,
    const float* __restrict__ hg, float* __restrict__ Ag,
    const float* __restrict__ W1top, const float* __restrict__ b1,
    const float* __restrict__ Wn1top, const float* __restrict__ bn1,
    const float* __restrict__ Wn2, const float* __restrict__ bn2,
    int updateH, float* __restrict__ hg_out) {
    int f0 = (tid & 31) * 4;
    int n2 = (tid >> 5) * 2;     // node pair 0,2,..,14
    {
        int node = tid & 15, j0 = (tid >> 4) * 8;
        float4 v0 = *(const float4*)&hg[(n0 + node) * HD + j0];
        float4 v1 = *(const float4*)&hg[(n0 + node) * HD + j0 + 4];
        T1[(j0 + 0) * 20 + node] = v0.x;
        T1[(j0 + 1) * 20 + node] = v0.y;
        T1[(j0 + 2) * 20 + node] = v0.z;
        T1[(j0 + 3) * 20 + node] = v0.w;
        T1[(j0 + 4) * 20 + node] = v1.x;
        T1[(j0 + 5) * 20 + node] = v1.y;
        T1[(j0 + 6) * 20 + node] = v1.z;
        T1[(j0 + 7) * 20 + node] = v1.w;
    }
    __syncthreads();
    float4 acc[2];
    {
        float4 bv = *(const float4*)&b1[f0];
        acc[0] = bv; acc[1] = bv;
#pragma unroll 4
        for (int j = 0; j < HD; j++) {
            float2 a = *(const float2*)&T1[j * 20 + n2];
            float4 w = *(const float4*)&W1top[j * HD + f0];
            acc[0].x += a.x * w.x; acc[0].y += a.x * w.y; acc[0].z += a.x * w.z; acc[0].w += a.x * w.w;
            acc[1].x += a.y * w.x; acc[1].y += a.y * w.y; acc[1].z += a.y * w.z; acc[1].w += a.y * w.w;
        }
        *(float4*)&Ag[(n0 + n2 + 0) * HD + f0] = acc[0];
        *(float4*)&Ag[(n0 + n2 + 1) * HD + f0] = acc[1];
    }
    if (updateH) {
        float4 bv = *(const float4*)&bn1[f0];
        acc[0] = bv; acc[1] = bv;
#pragma unroll 4
        for (int j = 0; j < HD; j++) {
            float2 a = *(const float2*)&T1[j * 20 + n2];
            float4 w = *(const float4*)&Wn1top[j * HD + f0];
            acc[0].x += a.x * w.x; acc[0].y += a.x * w.y; acc[0].z += a.x * w.z; acc[0].w += a.x * w.w;
            acc[1].x += a.y * w.x; acc[1].y += a.y * w.y; acc[1].z += a.y * w.z; acc[1].w += a.y * w.w;
        }
#pragma unroll
        for (int qq = 0; qq < 2; qq++) {
            T2[(f0 + 0) * 20 + n2 + qq] = silu_f(acc[qq].x);
            T2[(f0 + 1) * 20 + n2 + qq] = silu_f(acc[qq].y);
            T2[(f0 + 2) * 20 + n2 + qq] = silu_f(acc[qq].z);
            T2[(f0 + 3) * 20 + n2 + qq] = silu_f(acc[qq].w);
        }
        __syncthreads();
        bv = *(const float4*)&bn2[f0];
        acc[0] = bv; acc[1] = bv;
#pragma unroll 4
        for (int j = 0; j < HD; j++) {
            float2 a = *(const float2*)&T2[j * 20 + n2];
            float4 w = *(const float4*)&Wn2[j * HD + f0];
            acc[0].x += a.x * w.x; acc[0].y += a.x * w.y; acc[0].z += a.x * w.z; acc[0].w += a.x * w.w;
            acc[1].x += a.y * w.x; acc[1].y += a.y * w.y; acc[1].z += a.y * w.z; acc[1].w += a.y * w.w;
        }
#pragma unroll
        for (int qq = 0; qq < 2; qq++) {
            float4 h;
            h.x = T1[(f0 + 0) * 20 + n2 + qq] + acc[qq].x;
            h.y = T1[(f0 + 1) * 20 + n2 + qq] + acc[qq].y;
            h.z = T1[(f0 + 2) * 20 + n2 + qq] + acc[qq].z;
            h.w = T1[(f0 + 3) * 20 + n2 + qq] + acc[qq].w;
            *(float4*)&hg_out[(n0 + n2 + qq) * HD + f0] = h;
        }
    }
}

// ---------------- standalone ga (layer 0) ----------------
__global__ __launch_bounds__(256) void k_ga(
    const float* __restrict__ hg, float* __restrict__ Ag,
    const float* __restrict__ W1top, const float* __restrict__ b1,
    const float* __restrict__ Wn1top, const float* __restrict__ bn1,
    const float* __restrict__ Wn2, const float* __restrict__ bn2,
    int updateH, float* __restrict__ hg_out) {
    __shared__ float T1[HD * 20];
    __shared__ float T2[HD * 20];
    ga_body(T1, T2, blockIdx.x * 16, threadIdx.x, hg, Ag, W1top, b1,
            Wn1top, bn1, Wn2, bn2, updateH, hg_out);
}

// ---------------- MFMA node MLP helpers ----------------
__device__ __forceinline__ void stageB(short* Bb, const short* src, int rowF4, int colF4, int tid) {
#pragma unroll
    for (int s = 0; s < 8; s++) {
        int idx = s * 256 + tid;
        int f = idx >> 4, c4 = idx & 15;
        float4 v = ((const float4*)src)[f * rowF4 + colF4 + c4];
        *(float4*)((char*)Bb + ((idx * 16) ^ ((f & 7) << 4))) = v;
    }
}

__device__ __forceinline__ void nb_gemm(const short* X1, const short* Bb, floatx4* acc,
                                        int rowbase, int kOff, int quad, int c, int swz) {
#pragma unroll
    for (int ks = 0; ks < 4; ks++) {
        short8 a = *(const short8*)((const char*)X1 + rowbase + (((kOff + ks * 32 + quad * 8) * 2) ^ swz));
#pragma unroll
        for (int n = 0; n < 8; n++) {
            short8 b = *(const short8*)((const char*)Bb + ((((n * 16 + c) << 8) + (ks * 32 + quad * 8) * 2) ^ swz));
            acc[n] = __builtin_amdgcn_mfma_f32_16x16x32_bf16(a, b, acc[n], 0, 0, 0);
        }
    }
}

// ---------------- MFMA node MLP: 64 queries/block, 4 waves, 3 chained GEMMs ----------------
__global__ __launch_bounds__(256) void k_nb2(
    float* __restrict__ hq, const float* __restrict__ mg,
    const float* __restrict__ bn1, const float* __restrict__ bn2,
    const short* __restrict__ W1T, const short* __restrict__ W2T,
    const short* __restrict__ W3T, float* __restrict__ Bq) {
    __shared__ short X1[64 * 256];   // 32KB [q][k] swizzled (row&7)<<4
    __shared__ short Bb[128 * 128];  // 32KB [f][k] swizzled (f&7)<<4
    int tid = threadIdx.x;
    int q0 = blockIdx.x * 64;
    int wid = tid >> 6, lane = tid & 63, quad = lane >> 4, c = lane & 15;
    const int swz = (c & 7) << 4;

    {
        int q = tid >> 2, part = tid & 3;
        const float* src = (part < 2) ? &hq[(q0 + q) * HD + (part & 1) * 64]
                                      : &mg[(q0 + q) * HD + (part & 1) * 64];
        int wswz = (q & 7) << 4;
#pragma unroll
        for (int i = 0; i < 8; i++) {
            float4 a = ((const float4*)src)[2 * i];
            float4 b = ((const float4*)src)[2 * i + 1];
            short8 v;
            v[0] = f2bf(a.x); v[1] = f2bf(a.y); v[2] = f2bf(a.z); v[3] = f2bf(a.w);
            v[4] = f2bf(b.x); v[5] = f2bf(b.y); v[6] = f2bf(b.z); v[7] = f2bf(b.w);
            *(short8*)((char*)X1 + ((q * 512 + part * 128 + i * 16) ^ wswz)) = v;
        }
    }
    stageB(Bb, W1T, 32, 0, tid);    // Wn1 k-half 0
    __syncthreads();

    int row = wid * 16 + c;
    int rowbase = row * 512;
    floatx4 acc[8];
#pragma unroll
    for (int n = 0; n < 8; n++) acc[n] = (floatx4)0.f;
    nb_gemm(X1, Bb, acc, rowbase, 0, quad, c, swz);      // GEMM1 k 0..127 (h)
    __syncthreads();
    stageB(Bb, W1T, 32, 16, tid);   // Wn1 k-half 1
    __syncthreads();
    nb_gemm(X1, Bb, acc, rowbase, 128, quad, c, swz);    // GEMM1 k 128..255 (mg)
    __syncthreads();

#pragma unroll
    for (int n = 0; n < 8; n++) {
        int f = n * 16 + c;
        float b1v = bn1[f];
#pragma unroll
        for (int r = 0; r < 4; r++) {
            int rq = wid * 16 + quad * 4 + r;
            *(short*)((char*)X1 + ((rq * 512 + (128 + f) * 2) ^ ((rq & 7) << 4))) =
                f2bf(silu_f(acc[n][r] + b1v));
        }
    }
    stageB(Bb, W2T, 16, 0, tid);
    __syncthreads();

#pragma unroll
    for (int n = 0; n < 8; n++) acc[n] = (floatx4)0.f;
    nb_gemm(X1, Bb, acc, rowbase, 128, quad, c, swz);    // GEMM2: A = S region
    __syncthreads();

#pragma unroll
    for (int n = 0; n < 8; n++) {
        int f = n * 16 + c;
        float b2v2 = bn2[f];
#pragma unroll
        for (int r = 0; r < 4; r++) {
            int rq = wid * 16 + quad * 4 + r;
            int gq = q0 + rq;
            float hv = hq[gq * HD + f] + acc[n][r] + b2v2;
            hq[gq * HD + f] = hv;
            *(short*)((char*)X1 + ((rq * 512 + f * 2) ^ ((rq & 7) << 4))) = f2bf(hv);
        }
    }
    stageB(Bb, W3T, 16, 0, tid);
    __syncthreads();

#pragma unroll
    for (int n = 0; n < 8; n++) acc[n] = (floatx4)0.f;
    nb_gemm(X1, Bb, acc, rowbase, 0, quad, c, swz);      // GEMM3: A = h' region
#pragma unroll
    for (int n = 0; n < 8; n++) {
        int f = n * 16 + c;
#pragma unroll
        for (int r = 0; r < 4; r++) {
            int gq = q0 + wid * 16 + quad * 4 + r;
            Bq[gq * HD + f] = acc[n][r];
        }
    }
}

// ---------------- fused: edge blocks [0,1024) + ga rider [1024,1152) ----------------
// 512-thread blocks, 16 queries each: same per-wave structure as round 6 but 2x work
// per wsT staging + per block launch. ga rider runs two independent 16-node tiles
// (both halves in lockstep so ga_body's barriers align).
template <int OUTT, bool FIN, bool GA>
__global__ __launch_bounds__(512, 4) void k_edge_ga(
    const float* __restrict__ Ag, const float* __restrict__ Bq, float* __restrict__ x_q,
    const float* __restrict__ wdrow, const short* __restrict__ wsT,
    const float* __restrict__ b2v, const float* __restrict__ Wc, const float* __restrict__ cbp,
    const int* __restrict__ erow, const float* __restrict__ gridp,
    const float* __restrict__ qp, float* __restrict__ out, float* __restrict__ maggr,
    const float* __restrict__ hg, float* __restrict__ Ag2,
    const float* __restrict__ W1top, const float* __restrict__ b1,
    const float* __restrict__ Wn1top, const float* __restrict__ bn1,
    const float* __restrict__ Wn2g, const float* __restrict__ bn2g,
    int updateH, float* __restrict__ hg_out) {
    __shared__ union {
        struct { float T1a[HD * 20]; float T2a[HD * 20];
                 float T1b[HD * 20]; float T2b[HD * 20]; } ga;     // 40960 B
        struct { float misc[3072]; short lwsT[HD * HD]; } edge;    // 12288 + 32768 B
    } sm;
    int tid = threadIdx.x;

    if (GA && blockIdx.x >= EBLK) {
        int half = tid >> 8, t2 = tid & 255;
        float* T1 = half ? sm.ga.T1b : sm.ga.T1a;
        float* T2 = half ? sm.ga.T2b : sm.ga.T2a;
        ga_body(T1, T2, (blockIdx.x - EBLK) * 32 + half * 16, t2, hg, Ag2, W1top, b1,
                Wn1top, bn1, Wn2g, bn2g, updateH, hg_out);
        return;
    }

    float* sdist = sm.edge.misc;                 // 256
    float* scm   = sm.edge.misc + 256;           // 256
    float* sdir  = sm.edge.misc + 512;           // 768
    float* xs    = sm.edge.misc + 1280;          // 48
    float* scoef = sm.edge.misc + 1344;          // <= 1280
    int*   sgi   = (int*)(sm.edge.misc + 2624);  // 256
    short* lwsT  = sm.edge.lwsT;                 // 32 KB, XOR-swizzled

    int q0 = blockIdx.x * QB;
    int wid = tid >> 6, lane = tid & 63, quad = lane >> 4, c = lane & 15;

    if (tid < QB * 3) xs[tid] = x_q[q0 * 3 + tid];
    // stage wsT slice -> LDS, swizzled: byte ^= ((row&7)<<4), row = byte>>8
    {
        const float4* src = (const float4*)wsT;   // 2048 float4
#pragma unroll
        for (int s = 0; s < 4; s++) {
            int idx = s * 512 + tid;
            int byte = idx << 4;
            int swz = byte ^ (((byte >> 8) & 7) << 4);
            *(float4*)((char*)lwsT + swz) = src[idx];
        }
    }
    __syncthreads();
    if (tid < EB) {
        int e = tid, q = e >> 4;
        int gi = erow[q0 * DEG + e] - N_PTS;
        sgi[e] = gi;
        int gl = gi & (GPTS - 1);
        float r0 = gridp[gl * 3 + 0] - xs[q * 3 + 0];
        float r1 = gridp[gl * 3 + 1] - xs[q * 3 + 1];
        float r2 = gridp[gl * 3 + 2] - xs[q * 3 + 2];
        float dist = sqrtf(r0 * r0 + r1 * r1 + r2 * r2);
        float inv = 1.0f / (dist + 1e-8f);
        sdist[e] = dist;
        sdir[0 * EB + e] = r0 * inv;
        sdir[1 * EB + e] = r1 * inv;
        sdir[2 * EB + e] = r2 * inv;
        float cw = 0.5f * (__cosf(dist * 0.31415926535897931f) + 1.0f);
        scm[e] = (dist <= 10.0f) ? cw : 0.0f;
    }
    __syncthreads();

    int gi_[2]; float dist_[2];
#pragma unroll
    for (int mi = 0; mi < 2; mi++) {
        int e = (wid * 2 + mi) * 16 + c;
        gi_[mi] = sgi[e];
        dist_[mi] = sdist[e];
    }

    floatx4 acc[2][8];
#pragma unroll
    for (int mi = 0; mi < 2; mi++)
#pragma unroll
        for (int n = 0; n < 8; n++) acc[mi][n] = (floatx4)0.f;

    const int swz = (c & 7) << 4;      // lane-constant read swizzle

#pragma unroll
    for (int ch = 0; ch < 4; ch++) {
        int kb = ch * 32 + quad * 8;
        float4 wd0 = *(const float4*)(wdrow + kb);
        float4 wd1 = *(const float4*)(wdrow + kb + 4);
        short8 afr[2];
#pragma unroll
        for (int mi = 0; mi < 2; mi++) {
            int q = wid * 2 + mi;
            float dist = dist_[mi];
            const float4* ap = (const float4*)(Ag + gi_[mi] * HD + kb);
            float4 a0 = ap[0], a1 = ap[1];
            const float4* bp4 = (const float4*)(Bq + (q0 + q) * HD + kb);
            float4 b0 = bp4[0], b1 = bp4[1];
            short8 v;
            v[0] = f2bf(silu_f(a0.x + b0.x + dist * wd0.x));
            v[1] = f2bf(silu_f(a0.y + b0.y + dist * wd0.y));
            v[2] = f2bf(silu_f(a0.z + b0.z + dist * wd0.z));
            v[3] = f2bf(silu_f(a0.w + b0.w + dist * wd0.w));
            v[4] = f2bf(silu_f(a1.x + b1.x + dist * wd1.x));
            v[5] = f2bf(silu_f(a1.y + b1.y + dist * wd1.y));
            v[6] = f2bf(silu_f(a1.z + b1.z + dist * wd1.z));
            v[7] = f2bf(silu_f(a1.w + b1.w + dist * wd1.w));
            afr[mi] = v;
        }
#pragma unroll
        for (int n = 0; n < 8; n++) {
            int byte = ((n * 16 + c) << 8) + (kb << 1);
            short8 bfr = *(const short8*)((const char*)lwsT + (byte ^ swz));
            acc[0][n] = __builtin_amdgcn_mfma_f32_16x16x32_bf16(afr[0], bfr, acc[0][n], 0, 0, 0);
            acc[1][n] = __builtin_amdgcn_mfma_f32_16x16x32_bf16(afr[1], bfr, acc[1][n], 0, 0, 0);
        }
    }

#pragma unroll
    for (int mi = 0; mi < 2; mi++) {
        int q = wid * 2 + mi;
        int ebase = q * 16;
        float cmr[4];
#pragma unroll
        for (int r = 0; r < 4; r++) cmr[r] = scm[ebase + quad * 4 + r];
        float apc[4][OUTT];
#pragma unroll
        for (int r = 0; r < 4; r++)
#pragma unroll
            for (int t = 0; t < OUTT; t++) apc[r][t] = 0.f;
#pragma unroll
        for (int n = 0; n < 8; n++) {
            int f = n * 16 + c;
            float be2v = b2v[f];
            float wcv[OUTT];
            if (FIN) {
#pragma unroll
                for (int t = 0; t < OUTT; t++) wcv[t] = Wc[f * 5 + t];
            } else {
                wcv[0] = Wc[f];
            }
            float cs = 0.f;
#pragma unroll
            for (int r = 0; r < 4; r++) {
                float v = silu_f(acc[mi][n][r] + be2v) * cmr[r];
                cs += v;
#pragma unroll
                for (int t = 0; t < OUTT; t++) apc[r][t] += v * wcv[t];
            }
            cs += __shfl_xor(cs, 16, 64);
            cs += __shfl_xor(cs, 32, 64);
            if (!FIN && lane < 16) maggr[(q0 + q) * HD + f] = cs * 0.0625f;
        }
#pragma unroll
        for (int t = 0; t < OUTT; t++) {
#pragma unroll
            for (int r = 0; r < 4; r++) {
                float v = apc[r][t];
                v += __shfl_xor(v, 1, 64);
                v += __shfl_xor(v, 2, 64);
                v += __shfl_xor(v, 4, 64);
                v += __shfl_xor(v, 8, 64);
                if (c == 0) scoef[(ebase + quad * 4 + r) * OUTT + t] = v;
            }
        }
    }
    __syncthreads();

    if (tid < QB * 3 * OUTT) {
        int qq = tid / (3 * OUTT), rem = tid % (3 * OUTT), t = rem / 3, c2 = rem % 3;
        float cbv = cbp[t];
        float s = 0.f;
#pragma unroll 4
        for (int r = 0; r < 16; r++) {
            int ee = qq * 16 + r;
            s += (scoef[ee * OUTT + t] + cbv) * sdir[c2 * EB + ee];
        }
        float dd = s * 0.0625f;
        if (FIN) out[(q0 + qq) * 15 + t * 3 + c2] = xs[qq * 3 + c2] + dd - qp[(q0 + qq) * 3 + c2];
        else x_q[(q0 + qq) * 3 + c2] = xs[qq * 3 + c2] + dd;
    }
}

extern "C" void kernel_launch(void* const* d_in, const int* in_sizes, int n_in,
                              void* d_out, int out_size, void* d_ws, size_t ws_size,
                              hipStream_t stream) {
    float* out = (float*)d_out;
    int fill_blocks = (out_size + 255) / 256;

    static const int exp_sz[16] = { 49152, 524288, 1536, 131584, 512, 65536, 512, 384,
                                    3, 640, 5, 131072, 512, 65536, 512, 524288 };
    bool ok = (n_in == 16);
    for (int i = 0; ok && i < 16; i++) if (in_sizes[i] != exp_sz[i]) ok = false;
    if (!ok || ws_size < (size_t)40 * 1024 * 1024) {
        k_fillf<<<fill_blocks, 256, 0, stream>>>(out, 777.0f, out_size);
        return;
    }

    const float* qp    = (const float*)d_in[0];
    const float* codes = (const float*)d_in[1];
    const float* gridp = (const float*)d_in[2];
    const float* eW1   = (const float*)d_in[3];
    const float* eb1   = (const float*)d_in[4];
    const float* eW2   = (const float*)d_in[5];
    const float* eb2   = (const float*)d_in[6];
    const float* cW    = (const float*)d_in[7];
    const float* cb    = (const float*)d_in[8];
    const float* fcW   = (const float*)d_in[9];
    const float* fcb   = (const float*)d_in[10];
    const float* nW1   = (const float*)d_in[11];
    const float* nb1   = (const float*)d_in[12];
    const float* nW2   = (const float*)d_in[13];
    const float* nb2   = (const float*)d_in[14];
    const int*   erow  = (const int*)d_in[15];

    float* ws = (float*)d_ws;
    float* x_q  = ws;  ws += N_PTS * 3;
    float* h_q  = ws;  ws += N_PTS * HD;
    float* hg_a = ws;  ws += N_GRID * HD;
    float* hg_b = ws;  ws += N_GRID * HD;
    float* Ag0  = ws;  ws += N_GRID * HD;
    float* Ag1  = ws;  ws += N_GRID * HD;
    float* Bqb  = ws;  ws += N_PTS * HD;
    float* mgb  = ws;  ws += N_PTS * HD;
    short* wsT    = (short*)ws;        // 4 x 16384
    short* nW1T   = wsT + 65536;       // 3 x 32768
    short* nW2T   = nW1T + 98304;      // 3 x 16384
    short* W1midT = nW2T + 49152;      // 3 x 16384
    float* Agb[2] = { Ag0, Ag1 };

    k_init<<<2048, 256, 0, stream>>>(qp, codes, x_q, hg_a, h_q, Bqb);
    k_prep<<<(4 * HD * HD + 255) / 256, 256, 0, stream>>>(eW2, wsT);
    k_prep2<<<(3 * 32768 + 6 * 16384 + 255) / 256, 256, 0, stream>>>(nW1, nW2, eW1,
                                                                     nW1T, nW2T, W1midT);

    // layer-0 ga standalone: A_g(0), h_g(1)
    k_ga<<<GABLK, 256, 0, stream>>>(hg_a, Agb[0], eW1, eb1,
                                    nW1, nb1, nW2, nb2, 1, hg_b);
    float* hg_cur = hg_b;       // h_g for layer 1
    float* hg_next = hg_a;

    for (int i = 0; i < 4; i++) {
        int fin = (i == 3);
        const float* W1l = eW1 + i * 257 * 128;
        if (i > 0) {
            int p = i - 1;
            k_nb2<<<N_PTS / 64, 256, 0, stream>>>(h_q, mgb,
                                                  nb1 + p * 128, nb2 + p * 128,
                                                  nW1T + p * 32768, nW2T + p * 16384,
                                                  W1midT + p * 16384, Bqb);
        }
        if (!fin) {
            int L = i + 1;      // ga layer riding along
            const float* W1n = eW1 + L * 257 * 128;
            k_edge_ga<1, false, true><<<EBLK + GABLK2, 512, 0, stream>>>(
                Agb[i & 1], Bqb, x_q, W1l + 256 * 128, wsT + i * 16384, eb2 + i * 128,
                cW + i * 128, cb + i, erow, gridp, qp, out, mgb,
                hg_cur, Agb[L & 1], W1n, eb1 + L * 128,
                nW1 + L * 256 * 128, nb1 + L * 128, nW2 + L * 16384, nb2 + L * 128,
                (L < 3) ? 1 : 0, hg_next);
            float* tmp = hg_cur; hg_cur = hg_next; hg_next = tmp;
        } else {
            k_edge_ga<5, true, false><<<EBLK, 512, 0, stream>>>(
                Agb[i & 1], Bqb, x_q, W1l + 256 * 128, wsT + i * 16384, eb2 + i * 128,
                fcW, fcb, erow, gridp, qp, out, mgb,
                nullptr, nullptr, nullptr, nullptr,
                nullptr, nullptr, nullptr, nullptr, 0, nullptr);
        }
    }
}

// Round 8
// 370.420 us; speedup vs baseline: 1.1322x; 1.1322x over previous
//
#include <hip/hip_runtime.h>
#include <hip/hip_bf16.h>

typedef unsigned short u16;
typedef unsigned int u32;
typedef __attribute__((ext_vector_type(8))) short short8;
typedef __attribute__((ext_vector_type(4))) float floatx4;

#define N_PTS 16384
#define N_GRID 4096
#define GPTS 512
#define HD 128
#define DEG 16
#define QB 16
#define EB 256
#define EBLK (N_PTS / QB)    // 1024 edge blocks (512 threads, 16 queries each)

// fast silu: v_rcp_f32 instead of full-precision divide (rel err ~2^-22)
__device__ __forceinline__ float silu_f(float x) {
    return x * __builtin_amdgcn_rcpf(1.0f + __expf(-x));
}
__device__ __forceinline__ short f2bf(float x) { return (short)__bfloat16_as_ushort(__float2bfloat16(x)); }

__global__ void k_fillf(float* out, float v, int n) {
    int i = blockIdx.x * blockDim.x + threadIdx.x;
    if (i < n) out[i] = v;
}

__global__ void k_init(const float* __restrict__ qp, const float* __restrict__ codes,
                       float* __restrict__ x_q, float* __restrict__ h_g, float* __restrict__ h_q,
                       float* __restrict__ Bq) {
    int stride = gridDim.x * blockDim.x;
    int i0 = blockIdx.x * blockDim.x + threadIdx.x;
    for (int i = i0; i < N_PTS * 3; i += stride) x_q[i] = qp[i];
    for (int i = i0; i < N_GRID * HD; i += stride) h_g[i] = codes[i];
    for (int i = i0; i < N_PTS * HD; i += stride) { h_q[i] = 0.0f; Bq[i] = 0.0f; }
}

// transpose We2 -> bf16 wsT[layer][f*128+k]
__global__ void k_prep(const float* __restrict__ eW2, short* __restrict__ wsT) {
    int idx = blockIdx.x * blockDim.x + threadIdx.x;
    if (idx >= 4 * HD * HD) return;
    int l = idx >> 14, rem = idx & 16383, f = rem >> 7, k = rem & 127;
    wsT[idx] = f2bf(eW2[l * 16384 + k * HD + f]);
}

// bf16 transposes: nW1T[3][f*256+k], nW2T[3][f*128+k], W1midT[3][f*128+k], W1topT[4][f*128+k]
__global__ void k_prep2(const float* __restrict__ nW1, const float* __restrict__ nW2,
                        const float* __restrict__ eW1,
                        short* __restrict__ nW1T, short* __restrict__ nW2T,
                        short* __restrict__ W1midT, short* __restrict__ W1topT) {
    int idx = blockIdx.x * blockDim.x + threadIdx.x;
    if (idx < 3 * 32768) {
        int l = idx >> 15, r = idx & 32767, f = r >> 8, k = r & 255;
        nW1T[idx] = f2bf(nW1[l * 32768 + k * 128 + f]);
    } else if (idx < 3 * 32768 + 3 * 16384) {
        int j = idx - 3 * 32768;
        int l = j >> 14, r = j & 16383, f = r >> 7, k = r & 127;
        nW2T[j] = f2bf(nW2[l * 16384 + k * 128 + f]);
    } else if (idx < 3 * 32768 + 6 * 16384) {
        int j = idx - 3 * 32768 - 3 * 16384;
        int p = j >> 14, r = j & 16383, f = r >> 7, k = r & 127;
        W1midT[j] = f2bf(eW1[(p + 1) * 257 * 128 + (128 + k) * 128 + f]);
    } else if (idx < 3 * 32768 + 6 * 16384 + 4 * 16384) {
        int j = idx - 3 * 32768 - 6 * 16384;
        int l = j >> 14, r = j & 16383, f = r >> 7, k = r & 127;
        W1topT[j] = f2bf(eW1[l * 257 * 128 + k * 128 + f]);
    }
}

// ---------------- MFMA GEMM helpers (shared by k_nb2 / k_ga2) ----------------
__device__ __forceinline__ void stageB(short* Bb, const short* src, int rowF4, int colF4, int tid) {
#pragma unroll
    for (int s = 0; s < 8; s++) {
        int idx = s * 256 + tid;
        int f = idx >> 4, c4 = idx & 15;
        float4 v = ((const float4*)src)[f * rowF4 + colF4 + c4];
        *(float4*)((char*)Bb + ((idx * 16) ^ ((f & 7) << 4))) = v;
    }
}

__device__ __forceinline__ void nb_gemm(const short* X1, const short* Bb, floatx4* acc,
                                        int rowbase, int kOff, int quad, int c, int swz) {
#pragma unroll
    for (int ks = 0; ks < 4; ks++) {
        short8 a = *(const short8*)((const char*)X1 + rowbase + (((kOff + ks * 32 + quad * 8) * 2) ^ swz));
#pragma unroll
        for (int n = 0; n < 8; n++) {
            short8 b = *(const short8*)((const char*)Bb + ((((n * 16 + c) << 8) + (ks * 32 + quad * 8) * 2) ^ swz));
            acc[n] = __builtin_amdgcn_mfma_f32_16x16x32_bf16(a, b, acc[n], 0, 0, 0);
        }
    }
}

// ---------------- MFMA grid-node kernel: 64 nodes/block, 4 waves ----------------
// Ag = hg*W1top + b1; if updateH: hg' = hg + silu(hg*Wn1top+bn1)*Wn2 + bn2.
// Grid nodes receive no edges (m_aggr = 0) so only the h-half of Wn1 participates.
__global__ __launch_bounds__(256) void k_ga2(
    const float* __restrict__ hg, float* __restrict__ Ag,
    const short* __restrict__ W1topT, const float* __restrict__ b1,
    const short* __restrict__ Wn1T, const float* __restrict__ bn1,
    const short* __restrict__ Wn2T, const float* __restrict__ bn2,
    int updateH, float* __restrict__ hg_out) {
    __shared__ short X[64 * 128];    // 16KB [node][k] bf16, row-swizzled (row&7)<<4
    __shared__ short Bb[128 * 128];  // 32KB [f][k] bf16, f-swizzled
    int tid = threadIdx.x;
    int n0 = blockIdx.x * 64;
    int wid = tid >> 6, lane = tid & 63, quad = lane >> 4, c = lane & 15;
    const int swz = (c & 7) << 4;

    // stage X = bf16(hg): 4 threads/row, 32 floats each
    {
        int q = tid >> 2, part = tid & 3;
        const float* src = &hg[(n0 + q) * HD + part * 32];
        int wswz = (q & 7) << 4;
#pragma unroll
        for (int i = 0; i < 4; i++) {
            float4 a = ((const float4*)src)[2 * i];
            float4 b = ((const float4*)src)[2 * i + 1];
            short8 v;
            v[0] = f2bf(a.x); v[1] = f2bf(a.y); v[2] = f2bf(a.z); v[3] = f2bf(a.w);
            v[4] = f2bf(b.x); v[5] = f2bf(b.y); v[6] = f2bf(b.z); v[7] = f2bf(b.w);
            *(short8*)((char*)X + ((q * 256 + part * 64 + i * 16) ^ wswz)) = v;
        }
    }
    stageB(Bb, W1topT, 16, 0, tid);
    __syncthreads();

    int rowbase = (wid * 16 + c) * 256;
    floatx4 acc[8];
#pragma unroll
    for (int n = 0; n < 8; n++) acc[n] = (floatx4)0.f;
    nb_gemm(X, Bb, acc, rowbase, 0, quad, c, swz);       // GEMM1: Ag
#pragma unroll
    for (int n = 0; n < 8; n++) {
        int f = n * 16 + c;
        float bv = b1[f];
#pragma unroll
        for (int r = 0; r < 4; r++)
            Ag[(n0 + wid * 16 + quad * 4 + r) * HD + f] = acc[n][r] + bv;
    }
    if (!updateH) return;

    __syncthreads();                 // GEMM1 Bb reads done
    stageB(Bb, Wn1T, 32, 0, tid);    // h-half of Wn1 (256-stride rows, k 0..127)
    __syncthreads();
#pragma unroll
    for (int n = 0; n < 8; n++) acc[n] = (floatx4)0.f;
    nb_gemm(X, Bb, acc, rowbase, 0, quad, c, swz);       // GEMM2: pre-silu
    __syncthreads();                 // all X reads done before in-place overwrite
#pragma unroll
    for (int n = 0; n < 8; n++) {
        int f = n * 16 + c;
        float b1v = bn1[f];
#pragma unroll
        for (int r = 0; r < 4; r++) {
            int rq = wid * 16 + quad * 4 + r;
            *(short*)((char*)X + ((rq * 256 + f * 2) ^ ((rq & 7) << 4))) =
                f2bf(silu_f(acc[n][r] + b1v));
        }
    }
    stageB(Bb, Wn2T, 16, 0, tid);
    __syncthreads();
#pragma unroll
    for (int n = 0; n < 8; n++) acc[n] = (floatx4)0.f;
    nb_gemm(X, Bb, acc, rowbase, 0, quad, c, swz);       // GEMM3: delta
#pragma unroll
    for (int n = 0; n < 8; n++) {
        int f = n * 16 + c;
        float b2v2 = bn2[f];
#pragma unroll
        for (int r = 0; r < 4; r++) {
            int gn = n0 + wid * 16 + quad * 4 + r;
            hg_out[gn * HD + f] = hg[gn * HD + f] + acc[n][r] + b2v2;
        }
    }
}

// ---------------- MFMA node MLP: 64 queries/block, 4 waves, 3 chained GEMMs ----------------
__global__ __launch_bounds__(256) void k_nb2(
    float* __restrict__ hq, const float* __restrict__ mg,
    const float* __restrict__ bn1, const float* __restrict__ bn2,
    const short* __restrict__ W1T, const short* __restrict__ W2T,
    const short* __restrict__ W3T, float* __restrict__ Bq) {
    __shared__ short X1[64 * 256];   // 32KB [q][k] swizzled (row&7)<<4
    __shared__ short Bb[128 * 128];  // 32KB [f][k] swizzled (f&7)<<4
    int tid = threadIdx.x;
    int q0 = blockIdx.x * 64;
    int wid = tid >> 6, lane = tid & 63, quad = lane >> 4, c = lane & 15;
    const int swz = (c & 7) << 4;

    {
        int q = tid >> 2, part = tid & 3;
        const float* src = (part < 2) ? &hq[(q0 + q) * HD + (part & 1) * 64]
                                      : &mg[(q0 + q) * HD + (part & 1) * 64];
        int wswz = (q & 7) << 4;
#pragma unroll
        for (int i = 0; i < 8; i++) {
            float4 a = ((const float4*)src)[2 * i];
            float4 b = ((const float4*)src)[2 * i + 1];
            short8 v;
            v[0] = f2bf(a.x); v[1] = f2bf(a.y); v[2] = f2bf(a.z); v[3] = f2bf(a.w);
            v[4] = f2bf(b.x); v[5] = f2bf(b.y); v[6] = f2bf(b.z); v[7] = f2bf(b.w);
            *(short8*)((char*)X1 + ((q * 512 + part * 128 + i * 16) ^ wswz)) = v;
        }
    }
    stageB(Bb, W1T, 32, 0, tid);    // Wn1 k-half 0
    __syncthreads();

    int row = wid * 16 + c;
    int rowbase = row * 512;
    floatx4 acc[8];
#pragma unroll
    for (int n = 0; n < 8; n++) acc[n] = (floatx4)0.f;
    nb_gemm(X1, Bb, acc, rowbase, 0, quad, c, swz);      // GEMM1 k 0..127 (h)
    __syncthreads();
    stageB(Bb, W1T, 32, 16, tid);   // Wn1 k-half 1
    __syncthreads();
    nb_gemm(X1, Bb, acc, rowbase, 128, quad, c, swz);    // GEMM1 k 128..255 (mg)
    __syncthreads();

#pragma unroll
    for (int n = 0; n < 8; n++) {
        int f = n * 16 + c;
        float b1v = bn1[f];
#pragma unroll
        for (int r = 0; r < 4; r++) {
            int rq = wid * 16 + quad * 4 + r;
            *(short*)((char*)X1 + ((rq * 512 + (128 + f) * 2) ^ ((rq & 7) << 4))) =
                f2bf(silu_f(acc[n][r] + b1v));
        }
    }
    stageB(Bb, W2T, 16, 0, tid);
    __syncthreads();

#pragma unroll
    for (int n = 0; n < 8; n++) acc[n] = (floatx4)0.f;
    nb_gemm(X1, Bb, acc, rowbase, 128, quad, c, swz);    // GEMM2: A = S region
    __syncthreads();

#pragma unroll
    for (int n = 0; n < 8; n++) {
        int f = n * 16 + c;
        float b2v2 = bn2[f];
#pragma unroll
        for (int r = 0; r < 4; r++) {
            int rq = wid * 16 + quad * 4 + r;
            int gq = q0 + rq;
            float hv = hq[gq * HD + f] + acc[n][r] + b2v2;
            hq[gq * HD + f] = hv;
            *(short*)((char*)X1 + ((rq * 512 + f * 2) ^ ((rq & 7) << 4))) = f2bf(hv);
        }
    }
    stageB(Bb, W3T, 16, 0, tid);
    __syncthreads();

#pragma unroll
    for (int n = 0; n < 8; n++) acc[n] = (floatx4)0.f;
    nb_gemm(X1, Bb, acc, rowbase, 0, quad, c, swz);      // GEMM3: A = h' region
#pragma unroll
    for (int n = 0; n < 8; n++) {
        int f = n * 16 + c;
#pragma unroll
        for (int r = 0; r < 4; r++) {
            int gq = q0 + wid * 16 + quad * 4 + r;
            Bq[gq * HD + f] = acc[n][r];
        }
    }
}

// ---------------- pure edge kernel: 512 threads, 16 queries, no ga rider ----------------
template <int OUTT, bool FIN>
__global__ __launch_bounds__(512, 4) void k_edge(
    const float* __restrict__ Ag, const float* __restrict__ Bq, float* __restrict__ x_q,
    const float* __restrict__ wdrow, const short* __restrict__ wsT,
    const float* __restrict__ b2v, const float* __restrict__ Wc, const float* __restrict__ cbp,
    const int* __restrict__ erow, const float* __restrict__ gridp,
    const float* __restrict__ qp, float* __restrict__ out, float* __restrict__ maggr) {
    __shared__ float misc[3072];
    __shared__ short lwsT[HD * HD];    // 32KB, XOR-swizzled
    int tid = threadIdx.x;

    float* sdist = misc;                 // 256
    float* scm   = misc + 256;           // 256
    float* sdir  = misc + 512;           // 768
    float* xs    = misc + 1280;          // 48
    float* scoef = misc + 1344;          // <= 1280
    int*   sgi   = (int*)(misc + 2624);  // 256

    int q0 = blockIdx.x * QB;
    int wid = tid >> 6, lane = tid & 63, quad = lane >> 4, c = lane & 15;

    if (tid < QB * 3) xs[tid] = x_q[q0 * 3 + tid];
    // stage wsT slice -> LDS, swizzled: byte ^= ((row&7)<<4), row = byte>>8
    {
        const float4* src = (const float4*)wsT;   // 2048 float4
#pragma unroll
        for (int s = 0; s < 4; s++) {
            int idx = s * 512 + tid;
            int byte = idx << 4;
            int swz2 = byte ^ (((byte >> 8) & 7) << 4);
            *(float4*)((char*)lwsT + swz2) = src[idx];
        }
    }
    __syncthreads();
    if (tid < EB) {
        int e = tid, q = e >> 4;
        int gi = erow[q0 * DEG + e] - N_PTS;
        sgi[e] = gi;
        int gl = gi & (GPTS - 1);
        float r0 = gridp[gl * 3 + 0] - xs[q * 3 + 0];
        float r1 = gridp[gl * 3 + 1] - xs[q * 3 + 1];
        float r2 = gridp[gl * 3 + 2] - xs[q * 3 + 2];
        float dist = sqrtf(r0 * r0 + r1 * r1 + r2 * r2);
        float inv = 1.0f / (dist + 1e-8f);
        sdist[e] = dist;
        sdir[0 * EB + e] = r0 * inv;
        sdir[1 * EB + e] = r1 * inv;
        sdir[2 * EB + e] = r2 * inv;
        float cw = 0.5f * (__cosf(dist * 0.31415926535897931f) + 1.0f);
        scm[e] = (dist <= 10.0f) ? cw : 0.0f;
    }
    __syncthreads();

    int gi_[2]; float dist_[2];
#pragma unroll
    for (int mi = 0; mi < 2; mi++) {
        int e = (wid * 2 + mi) * 16 + c;
        gi_[mi] = sgi[e];
        dist_[mi] = sdist[e];
    }

    floatx4 acc[2][8];
#pragma unroll
    for (int mi = 0; mi < 2; mi++)
#pragma unroll
        for (int n = 0; n < 8; n++) acc[mi][n] = (floatx4)0.f;

    const int swz = (c & 7) << 4;      // lane-constant read swizzle

#pragma unroll
    for (int ch = 0; ch < 4; ch++) {
        int kb = ch * 32 + quad * 8;
        float4 wd0 = *(const float4*)(wdrow + kb);
        float4 wd1 = *(const float4*)(wdrow + kb + 4);
        short8 afr[2];
#pragma unroll
        for (int mi = 0; mi < 2; mi++) {
            int q = wid * 2 + mi;
            float dist = dist_[mi];
            const float4* ap = (const float4*)(Ag + gi_[mi] * HD + kb);
            float4 a0 = ap[0], a1 = ap[1];
            const float4* bp4 = (const float4*)(Bq + (q0 + q) * HD + kb);
            float4 b0 = bp4[0], b1 = bp4[1];
            short8 v;
            v[0] = f2bf(silu_f(a0.x + b0.x + dist * wd0.x));
            v[1] = f2bf(silu_f(a0.y + b0.y + dist * wd0.y));
            v[2] = f2bf(silu_f(a0.z + b0.z + dist * wd0.z));
            v[3] = f2bf(silu_f(a0.w + b0.w + dist * wd0.w));
            v[4] = f2bf(silu_f(a1.x + b1.x + dist * wd1.x));
            v[5] = f2bf(silu_f(a1.y + b1.y + dist * wd1.y));
            v[6] = f2bf(silu_f(a1.z + b1.z + dist * wd1.z));
            v[7] = f2bf(silu_f(a1.w + b1.w + dist * wd1.w));
            afr[mi] = v;
        }
#pragma unroll
        for (int n = 0; n < 8; n++) {
            int byte = ((n * 16 + c) << 8) + (kb << 1);
            short8 bfr = *(const short8*)((const char*)lwsT + (byte ^ swz));
            acc[0][n] = __builtin_amdgcn_mfma_f32_16x16x32_bf16(afr[0], bfr, acc[0][n], 0, 0, 0);
            acc[1][n] = __builtin_amdgcn_mfma_f32_16x16x32_bf16(afr[1], bfr, acc[1][n], 0, 0, 0);
        }
    }

#pragma unroll
    for (int mi = 0; mi < 2; mi++) {
        int q = wid * 2 + mi;
        int ebase = q * 16;
        float cmr[4];
#pragma unroll
        for (int r = 0; r < 4; r++) cmr[r] = scm[ebase + quad * 4 + r];
        float apc[4][OUTT];
#pragma unroll
        for (int r = 0; r < 4; r++)
#pragma unroll
            for (int t = 0; t < OUTT; t++) apc[r][t] = 0.f;
#pragma unroll
        for (int n = 0; n < 8; n++) {
            int f = n * 16 + c;
            float be2v = b2v[f];
            float wcv[OUTT];
            if (FIN) {
#pragma unroll
                for (int t = 0; t < OUTT; t++) wcv[t] = Wc[f * 5 + t];
            } else {
                wcv[0] = Wc[f];
            }
            float cs = 0.f;
#pragma unroll
            for (int r = 0; r < 4; r++) {
                float v = silu_f(acc[mi][n][r] + be2v) * cmr[r];
                cs += v;
#pragma unroll
                for (int t = 0; t < OUTT; t++) apc[r][t] += v * wcv[t];
            }
            cs += __shfl_xor(cs, 16, 64);
            cs += __shfl_xor(cs, 32, 64);
            if (!FIN && lane < 16) maggr[(q0 + q) * HD + f] = cs * 0.0625f;
        }
#pragma unroll
        for (int t = 0; t < OUTT; t++) {
#pragma unroll
            for (int r = 0; r < 4; r++) {
                float v = apc[r][t];
                v += __shfl_xor(v, 1, 64);
                v += __shfl_xor(v, 2, 64);
                v += __shfl_xor(v, 4, 64);
                v += __shfl_xor(v, 8, 64);
                if (c == 0) scoef[(ebase + quad * 4 + r) * OUTT + t] = v;
            }
        }
    }
    __syncthreads();

    if (tid < QB * 3 * OUTT) {
        int qq = tid / (3 * OUTT), rem = tid % (3 * OUTT), t = rem / 3, c2 = rem % 3;
        float cbv = cbp[t];
        float s = 0.f;
#pragma unroll 4
        for (int r = 0; r < 16; r++) {
            int ee = qq * 16 + r;
            s += (scoef[ee * OUTT + t] + cbv) * sdir[c2 * EB + ee];
        }
        float dd = s * 0.0625f;
        if (FIN) out[(q0 + qq) * 15 + t * 3 + c2] = xs[qq * 3 + c2] + dd - qp[(q0 + qq) * 3 + c2];
        else x_q[(q0 + qq) * 3 + c2] = xs[qq * 3 + c2] + dd;
    }
}

extern "C" void kernel_launch(void* const* d_in, const int* in_sizes, int n_in,
                              void* d_out, int out_size, void* d_ws, size_t ws_size,
                              hipStream_t stream) {
    float* out = (float*)d_out;
    int fill_blocks = (out_size + 255) / 256;

    static const int exp_sz[16] = { 49152, 524288, 1536, 131584, 512, 65536, 512, 384,
                                    3, 640, 5, 131072, 512, 65536, 512, 524288 };
    bool ok = (n_in == 16);
    for (int i = 0; ok && i < 16; i++) if (in_sizes[i] != exp_sz[i]) ok = false;
    if (!ok || ws_size < (size_t)40 * 1024 * 1024) {
        k_fillf<<<fill_blocks, 256, 0, stream>>>(out, 777.0f, out_size);
        return;
    }

    const float* qp    = (const float*)d_in[0];
    const float* codes = (const float*)d_in[1];
    const float* gridp = (const float*)d_in[2];
    const float* eW1   = (const float*)d_in[3];
    const float* eb1   = (const float*)d_in[4];
    const float* eW2   = (const float*)d_in[5];
    const float* eb2   = (const float*)d_in[6];
    const float* cW    = (const float*)d_in[7];
    const float* cb    = (const float*)d_in[8];
    const float* fcW   = (const float*)d_in[9];
    const float* fcb   = (const float*)d_in[10];
    const float* nW1   = (const float*)d_in[11];
    const float* nb1   = (const float*)d_in[12];
    const float* nW2   = (const float*)d_in[13];
    const float* nb2   = (const float*)d_in[14];
    const int*   erow  = (const int*)d_in[15];

    float* ws = (float*)d_ws;
    float* x_q  = ws;  ws += N_PTS * 3;
    float* h_q  = ws;  ws += N_PTS * HD;
    float* hg_a = ws;  ws += N_GRID * HD;
    float* hg_b = ws;  ws += N_GRID * HD;
    float* Ag0  = ws;  ws += N_GRID * HD;
    float* Ag1  = ws;  ws += N_GRID * HD;
    float* Ag2  = ws;  ws += N_GRID * HD;
    float* Ag3  = ws;  ws += N_GRID * HD;
    float* Bqb  = ws;  ws += N_PTS * HD;
    float* mgb  = ws;  ws += N_PTS * HD;
    short* wsT    = (short*)ws;        // 4 x 16384
    short* nW1T   = wsT + 65536;       // 3 x 32768
    short* nW2T   = nW1T + 98304;      // 3 x 16384
    short* W1midT = nW2T + 49152;      // 3 x 16384
    short* W1topT = W1midT + 49152;    // 4 x 16384
    float* Agb[4] = { Ag0, Ag1, Ag2, Ag3 };
    float* hgs[2] = { hg_a, hg_b };

    k_init<<<2048, 256, 0, stream>>>(qp, codes, x_q, hg_a, h_q, Bqb);
    k_prep<<<(4 * HD * HD + 255) / 256, 256, 0, stream>>>(eW2, wsT);
    k_prep2<<<(3 * 32768 + 6 * 16384 + 4 * 16384 + 255) / 256, 256, 0, stream>>>(
        nW1, nW2, eW1, nW1T, nW2T, W1midT, W1topT);

    // grid-node pipeline: all 4 layers up front (independent of edges)
    for (int L = 0; L < 4; L++) {
        int nl = (L < 3) ? L : 0;   // Wn1T/Wn2T unused when updateH=0
        k_ga2<<<N_GRID / 64, 256, 0, stream>>>(
            hgs[L & 1], Agb[L], W1topT + L * 16384, eb1 + L * 128,
            nW1T + nl * 32768, nb1 + L * 128, nW2T + nl * 16384, nb2 + L * 128,
            (L < 3) ? 1 : 0, hgs[(L + 1) & 1]);
    }

    for (int i = 0; i < 4; i++) {
        int fin = (i == 3);
        const float* W1l = eW1 + i * 257 * 128;
        if (i > 0) {
            int p = i - 1;
            k_nb2<<<N_PTS / 64, 256, 0, stream>>>(h_q, mgb,
                                                  nb1 + p * 128, nb2 + p * 128,
                                                  nW1T + p * 32768, nW2T + p * 16384,
                                                  W1midT + p * 16384, Bqb);
        }
        if (!fin) {
            k_edge<1, false><<<EBLK, 512, 0, stream>>>(
                Agb[i], Bqb, x_q, W1l + 256 * 128, wsT + i * 16384, eb2 + i * 128,
                cW + i * 128, cb + i, erow, gridp, qp, out, mgb);
        } else {
            k_edge<5, true><<<EBLK, 512, 0, stream>>>(
                Agb[3], Bqb, x_q, W1l + 256 * 128, wsT + i * 16384, eb2 + i * 128,
                fcW, fcb, erow, gridp, qp, out, mgb);
        }
    }
}

// Round 10
// 345.221 us; speedup vs baseline: 1.2149x; 1.0730x over previous
//
#include <hip/hip_runtime.h>
#include <hip/hip_bf16.h>

typedef unsigned short u16;
typedef unsigned int u32;
typedef __attribute__((ext_vector_type(8))) short short8;
typedef __attribute__((ext_vector_type(4))) short shortx4;
typedef __attribute__((ext_vector_type(4))) float floatx4;

#define N_PTS 16384
#define N_GRID 4096
#define GPTS 512
#define HD 128
#define DEG 16
#define QB 16
#define EB 256
#define EBLK (N_PTS / QB)    // 1024 edge blocks (512 threads, 16 queries each)

// fast silu: v_rcp_f32 instead of full-precision divide (rel err ~2^-22)
__device__ __forceinline__ float silu_f(float x) {
    return x * __builtin_amdgcn_rcpf(1.0f + __expf(-x));
}
__device__ __forceinline__ short f2bf(float x) { return (short)__bfloat16_as_ushort(__float2bfloat16(x)); }

__global__ void k_fillf(float* out, float v, int n) {
    int i = blockIdx.x * blockDim.x + threadIdx.x;
    if (i < n) out[i] = v;
}

__global__ void k_init(const float* __restrict__ qp, const float* __restrict__ codes,
                       float* __restrict__ x_q, float* __restrict__ h_g, float* __restrict__ h_q,
                       float* __restrict__ Bq) {
    int stride = gridDim.x * blockDim.x;
    int i0 = blockIdx.x * blockDim.x + threadIdx.x;
    for (int i = i0; i < N_PTS * 3; i += stride) x_q[i] = qp[i];
    for (int i = i0; i < N_GRID * HD; i += stride) h_g[i] = codes[i];
    for (int i = i0; i < N_PTS * HD; i += stride) { h_q[i] = 0.0f; Bq[i] = 0.0f; }
}

// transpose We2 -> bf16 wsT[layer][f*128+k]
__global__ void k_prep(const float* __restrict__ eW2, short* __restrict__ wsT) {
    int idx = blockIdx.x * blockDim.x + threadIdx.x;
    if (idx >= 4 * HD * HD) return;
    int l = idx >> 14, rem = idx & 16383, f = rem >> 7, k = rem & 127;
    wsT[idx] = f2bf(eW2[l * 16384 + k * HD + f]);
}

// bf16 transposes: nW1T[3][f*256+k], nW2T[3][f*128+k], W1midT[3][f*128+k], W1topT[4][f*128+k]
__global__ void k_prep2(const float* __restrict__ nW1, const float* __restrict__ nW2,
                        const float* __restrict__ eW1,
                        short* __restrict__ nW1T, short* __restrict__ nW2T,
                        short* __restrict__ W1midT, short* __restrict__ W1topT) {
    int idx = blockIdx.x * blockDim.x + threadIdx.x;
    if (idx < 3 * 32768) {
        int l = idx >> 15, r = idx & 32767, f = r >> 8, k = r & 255;
        nW1T[idx] = f2bf(nW1[l * 32768 + k * 128 + f]);
    } else if (idx < 3 * 32768 + 3 * 16384) {
        int j = idx - 3 * 32768;
        int l = j >> 14, r = j & 16383, f = r >> 7, k = r & 127;
        nW2T[j] = f2bf(nW2[l * 16384 + k * 128 + f]);
    } else if (idx < 3 * 32768 + 6 * 16384) {
        int j = idx - 3 * 32768 - 3 * 16384;
        int p = j >> 14, r = j & 16383, f = r >> 7, k = r & 127;
        W1midT[j] = f2bf(eW1[(p + 1) * 257 * 128 + (128 + k) * 128 + f]);
    } else if (idx < 3 * 32768 + 6 * 16384 + 4 * 16384) {
        int j = idx - 3 * 32768 - 6 * 16384;
        int l = j >> 14, r = j & 16383, f = r >> 7, k = r & 127;
        W1topT[j] = f2bf(eW1[l * 257 * 128 + k * 128 + f]);
    }
}

// ---------------- MFMA GEMM helpers ----------------
__device__ __forceinline__ void stageB(short* Bb, const short* src, int rowF4, int colF4, int tid) {
#pragma unroll
    for (int s = 0; s < 8; s++) {
        int idx = s * 256 + tid;
        int f = idx >> 4, c4 = idx & 15;
        float4 v = ((const float4*)src)[f * rowF4 + colF4 + c4];
        *(float4*)((char*)Bb + ((idx * 16) ^ ((f & 7) << 4))) = v;
    }
}

__device__ __forceinline__ void stageB512(short* Bb, const short* src, int rowF4, int colF4, int tid) {
#pragma unroll
    for (int s = 0; s < 4; s++) {
        int idx = s * 512 + tid;
        int f = idx >> 4, c4 = idx & 15;
        float4 v = ((const float4*)src)[f * rowF4 + colF4 + c4];
        *(float4*)((char*)Bb + ((idx * 16) ^ ((f & 7) << 4))) = v;
    }
}

__device__ __forceinline__ void nb_gemm(const short* X1, const short* Bb, floatx4* acc,
                                        int rowbase, int kOff, int quad, int c, int swz) {
#pragma unroll
    for (int ks = 0; ks < 4; ks++) {
        short8 a = *(const short8*)((const char*)X1 + rowbase + (((kOff + ks * 32 + quad * 8) * 2) ^ swz));
#pragma unroll
        for (int n = 0; n < 8; n++) {
            short8 b = *(const short8*)((const char*)Bb + ((((n * 16 + c) << 8) + (ks * 32 + quad * 8) * 2) ^ swz));
            acc[n] = __builtin_amdgcn_mfma_f32_16x16x32_bf16(a, b, acc[n], 0, 0, 0);
        }
    }
}

// 16-row GEMM: A = X[16 rows x (kOffX..kOffX+128)], B-col-tile = wid. One MFMA tile.
__device__ __forceinline__ void gemm16(const short* X, const short* Bb, floatx4& acc,
                                       int kOffX, int wid, int quad, int c, int swz) {
#pragma unroll
    for (int ks = 0; ks < 4; ks++) {
        int k = ks * 32 + quad * 8;
        short8 a = *(const short8*)((const char*)X + ((c * 512 + (kOffX + k) * 2) ^ swz));
        short8 b = *(const short8*)((const char*)Bb + ((((wid * 16 + c) << 8) + k * 2) ^ swz));
        acc = __builtin_amdgcn_mfma_f32_16x16x32_bf16(a, b, acc, 0, 0, 0);
    }
}

// ---------------- MFMA grid-node kernel: 64 nodes/block, 4 waves ----------------
__global__ __launch_bounds__(256) void k_ga2(
    const float* __restrict__ hg, float* __restrict__ Ag,
    const short* __restrict__ W1topT, const float* __restrict__ b1,
    const short* __restrict__ Wn1T, const float* __restrict__ bn1,
    const short* __restrict__ Wn2T, const float* __restrict__ bn2,
    int updateH, float* __restrict__ hg_out) {
    __shared__ short X[64 * 128];    // 16KB [node][k] bf16, row-swizzled (row&7)<<4
    __shared__ short Bb[128 * 128];  // 32KB [f][k] bf16, f-swizzled
    int tid = threadIdx.x;
    int n0 = blockIdx.x * 64;
    int wid = tid >> 6, lane = tid & 63, quad = lane >> 4, c = lane & 15;
    const int swz = (c & 7) << 4;

    {
        int q = tid >> 2, part = tid & 3;
        const float* src = &hg[(n0 + q) * HD + part * 32];
        int wswz = (q & 7) << 4;
#pragma unroll
        for (int i = 0; i < 4; i++) {
            float4 a = ((const float4*)src)[2 * i];
            float4 b = ((const float4*)src)[2 * i + 1];
            short8 v;
            v[0] = f2bf(a.x); v[1] = f2bf(a.y); v[2] = f2bf(a.z); v[3] = f2bf(a.w);
            v[4] = f2bf(b.x); v[5] = f2bf(b.y); v[6] = f2bf(b.z); v[7] = f2bf(b.w);
            *(short8*)((char*)X + ((q * 256 + part * 64 + i * 16) ^ wswz)) = v;
        }
    }
    stageB(Bb, W1topT, 16, 0, tid);
    __syncthreads();

    int rowbase = (wid * 16 + c) * 256;
    floatx4 acc[8];
#pragma unroll
    for (int n = 0; n < 8; n++) acc[n] = (floatx4)0.f;
    nb_gemm(X, Bb, acc, rowbase, 0, quad, c, swz);       // GEMM1: Ag
#pragma unroll
    for (int n = 0; n < 8; n++) {
        int f = n * 16 + c;
        float bv = b1[f];
#pragma unroll
        for (int r = 0; r < 4; r++)
            Ag[(n0 + wid * 16 + quad * 4 + r) * HD + f] = acc[n][r] + bv;
    }
    if (!updateH) return;

    __syncthreads();
    stageB(Bb, Wn1T, 32, 0, tid);    // h-half of Wn1
    __syncthreads();
#pragma unroll
    for (int n = 0; n < 8; n++) acc[n] = (floatx4)0.f;
    nb_gemm(X, Bb, acc, rowbase, 0, quad, c, swz);       // GEMM2: pre-silu
    __syncthreads();
#pragma unroll
    for (int n = 0; n < 8; n++) {
        int f = n * 16 + c;
        float b1v = bn1[f];
#pragma unroll
        for (int r = 0; r < 4; r++) {
            int rq = wid * 16 + quad * 4 + r;
            *(short*)((char*)X + ((rq * 256 + f * 2) ^ ((rq & 7) << 4))) =
                f2bf(silu_f(acc[n][r] + b1v));
        }
    }
    stageB(Bb, Wn2T, 16, 0, tid);
    __syncthreads();
#pragma unroll
    for (int n = 0; n < 8; n++) acc[n] = (floatx4)0.f;
    nb_gemm(X, Bb, acc, rowbase, 0, quad, c, swz);       // GEMM3: delta
#pragma unroll
    for (int n = 0; n < 8; n++) {
        int f = n * 16 + c;
        float b2v2 = bn2[f];
#pragma unroll
        for (int r = 0; r < 4; r++) {
            int gn = n0 + wid * 16 + quad * 4 + r;
            hg_out[gn * HD + f] = hg[gn * HD + f] + acc[n][r] + b2v2;
        }
    }
}

// ---------------- fused edge + node-MLP kernel ----------------
// 512 threads, 16 queries. All DEG=16 edges of a query are in-block, so m_aggr is
// block-local; the node MLP (h update) + next-layer Bq are fused into the epilogue:
// Xn[16][256] = [h||m_aggr] bf16; 3 GEMMs with weights staged into the dead lwsT region.
template <int OUTT, bool FIN>
__global__ __launch_bounds__(512, 3) void k_edge(
    const float* __restrict__ Ag, float* __restrict__ Bq, float* __restrict__ x_q,
    const float* __restrict__ wdrow, const short* __restrict__ wsT,
    const float* __restrict__ b2v, const float* __restrict__ Wc, const float* __restrict__ cbp,
    const int* __restrict__ erow, const float* __restrict__ gridp,
    const float* __restrict__ qp, float* __restrict__ out,
    const float* __restrict__ bn1, const float* __restrict__ bn2,
    const short* __restrict__ Wn1T, const short* __restrict__ Wn2T,
    const short* __restrict__ W1midT, float* __restrict__ hq) {
    __shared__ float misc[3072];       // 12KB
    __shared__ short Xn[16 * 256];     // 8KB node-MLP A-matrix, row-swizzled
    __shared__ short lwsT[HD * HD];    // 32KB: We2 during K-loop; weight stage after
    int tid = threadIdx.x;

    float* sdist = misc;                 // 256
    float* scm   = misc + 256;           // 256
    float* sdir  = misc + 512;           // 768
    float* xs    = misc + 1280;          // 48
    float* scoef = misc + 1344;          // <= 1280
    int*   sgi   = (int*)(misc + 2624);  // 256

    int q0 = blockIdx.x * QB;
    int wid = tid >> 6, lane = tid & 63, quad = lane >> 4, c = lane & 15;

    if (tid < QB * 3) xs[tid] = x_q[q0 * 3 + tid];
    // stage We2 slice -> lwsT, swizzled
    {
        const float4* src = (const float4*)wsT;   // 2048 float4
#pragma unroll
        for (int s = 0; s < 4; s++) {
            int idx = s * 512 + tid;
            int byte = idx << 4;
            int swz2 = byte ^ (((byte >> 8) & 7) << 4);
            *(float4*)((char*)lwsT + swz2) = src[idx];
        }
    }
    __syncthreads();
    if (tid < EB) {
        int e = tid, q = e >> 4;
        int gi = erow[q0 * DEG + e] - N_PTS;
        sgi[e] = gi;
        int gl = gi & (GPTS - 1);
        float r0 = gridp[gl * 3 + 0] - xs[q * 3 + 0];
        float r1 = gridp[gl * 3 + 1] - xs[q * 3 + 1];
        float r2 = gridp[gl * 3 + 2] - xs[q * 3 + 2];
        float dist = sqrtf(r0 * r0 + r1 * r1 + r2 * r2);
        float inv = 1.0f / (dist + 1e-8f);
        sdist[e] = dist;
        sdir[0 * EB + e] = r0 * inv;
        sdir[1 * EB + e] = r1 * inv;
        sdir[2 * EB + e] = r2 * inv;
        float cw = 0.5f * (__cosf(dist * 0.31415926535897931f) + 1.0f);
        scm[e] = (dist <= 10.0f) ? cw : 0.0f;
    }
    __syncthreads();

    int gi_[2]; float dist_[2];
#pragma unroll
    for (int mi = 0; mi < 2; mi++) {
        int e = (wid * 2 + mi) * 16 + c;
        gi_[mi] = sgi[e];
        dist_[mi] = sdist[e];
    }

    floatx4 acc[2][8];
#pragma unroll
    for (int mi = 0; mi < 2; mi++)
#pragma unroll
        for (int n = 0; n < 8; n++) acc[mi][n] = (floatx4)0.f;

    const int swz = (c & 7) << 4;

#pragma unroll
    for (int ch = 0; ch < 4; ch++) {
        int kb = ch * 32 + quad * 8;
        float4 wd0 = *(const float4*)(wdrow + kb);
        float4 wd1 = *(const float4*)(wdrow + kb + 4);
        short8 afr[2];
#pragma unroll
        for (int mi = 0; mi < 2; mi++) {
            int q = wid * 2 + mi;
            float dist = dist_[mi];
            const float4* ap = (const float4*)(Ag + gi_[mi] * HD + kb);
            float4 a0 = ap[0], a1 = ap[1];
            const float4* bp4 = (const float4*)(Bq + (q0 + q) * HD + kb);
            float4 b0 = bp4[0], b1 = bp4[1];
            short8 v;
            v[0] = f2bf(silu_f(a0.x + b0.x + dist * wd0.x));
            v[1] = f2bf(silu_f(a0.y + b0.y + dist * wd0.y));
            v[2] = f2bf(silu_f(a0.z + b0.z + dist * wd0.z));
            v[3] = f2bf(silu_f(a0.w + b0.w + dist * wd0.w));
            v[4] = f2bf(silu_f(a1.x + b1.x + dist * wd1.x));
            v[5] = f2bf(silu_f(a1.y + b1.y + dist * wd1.y));
            v[6] = f2bf(silu_f(a1.z + b1.z + dist * wd1.z));
            v[7] = f2bf(silu_f(a1.w + b1.w + dist * wd1.w));
            afr[mi] = v;
        }
#pragma unroll
        for (int n = 0; n < 8; n++) {
            int byte = ((n * 16 + c) << 8) + (kb << 1);
            short8 bfr = *(const short8*)((const char*)lwsT + (byte ^ swz));
            acc[0][n] = __builtin_amdgcn_mfma_f32_16x16x32_bf16(afr[0], bfr, acc[0][n], 0, 0, 0);
            acc[1][n] = __builtin_amdgcn_mfma_f32_16x16x32_bf16(afr[1], bfr, acc[1][n], 0, 0, 0);
        }
    }

#pragma unroll
    for (int mi = 0; mi < 2; mi++) {
        int q = wid * 2 + mi;
        int ebase = q * 16;
        float cmr[4];
#pragma unroll
        for (int r = 0; r < 4; r++) cmr[r] = scm[ebase + quad * 4 + r];
        float apc[4][OUTT];
#pragma unroll
        for (int r = 0; r < 4; r++)
#pragma unroll
            for (int t = 0; t < OUTT; t++) apc[r][t] = 0.f;
#pragma unroll
        for (int n = 0; n < 8; n++) {
            int f = n * 16 + c;
            float be2v = b2v[f];
            float wcv[OUTT];
            if (FIN) {
#pragma unroll
                for (int t = 0; t < OUTT; t++) wcv[t] = Wc[f * 5 + t];
            } else {
                wcv[0] = Wc[f];
            }
            float cs = 0.f;
#pragma unroll
            for (int r = 0; r < 4; r++) {
                float v = silu_f(acc[mi][n][r] + be2v) * cmr[r];
                cs += v;
#pragma unroll
                for (int t = 0; t < OUTT; t++) apc[r][t] += v * wcv[t];
            }
            cs += __shfl_xor(cs, 16, 64);
            cs += __shfl_xor(cs, 32, 64);
            // m_aggr -> LDS Xn (bf16) instead of global
            if (!FIN && lane < 16)
                *(short*)((char*)Xn + ((q * 512 + (128 + f) * 2) ^ ((q & 7) << 4))) =
                    f2bf(cs * 0.0625f);
        }
#pragma unroll
        for (int t = 0; t < OUTT; t++) {
#pragma unroll
            for (int r = 0; r < 4; r++) {
                float v = apc[r][t];
                v += __shfl_xor(v, 1, 64);
                v += __shfl_xor(v, 2, 64);
                v += __shfl_xor(v, 4, 64);
                v += __shfl_xor(v, 8, 64);
                if (c == 0) scoef[(ebase + quad * 4 + r) * OUTT + t] = v;
            }
        }
    }
    __syncthreads();   // scoef + Xn m_aggr ready; lwsT K-loop reads done

    if (tid < QB * 3 * OUTT) {
        int qq = tid / (3 * OUTT), rem = tid % (3 * OUTT), t = rem / 3, c2 = rem % 3;
        float cbv = cbp[t];
        float s = 0.f;
#pragma unroll 4
        for (int r = 0; r < 16; r++) {
            int ee = qq * 16 + r;
            s += (scoef[ee * OUTT + t] + cbv) * sdir[c2 * EB + ee];
        }
        float dd = s * 0.0625f;
        if (FIN) out[(q0 + qq) * 15 + t * 3 + c2] = xs[qq * 3 + c2] + dd - qp[(q0 + qq) * 3 + c2];
        else x_q[(q0 + qq) * 3 + c2] = xs[qq * 3 + c2] + dd;
    }
    if (FIN) return;

    // ---- fused node MLP for this block's 16 queries ----
    // stage h (f32 -> bf16) into Xn k0..127
    {
        int q = tid >> 5, f0 = (tid & 31) * 4;
        float4 h4 = *(const float4*)&hq[(q0 + q) * HD + f0];
        shortx4 v;
        v[0] = f2bf(h4.x); v[1] = f2bf(h4.y); v[2] = f2bf(h4.z); v[3] = f2bf(h4.w);
        *(shortx4*)((char*)Xn + ((q * 512 + f0 * 2) ^ ((q & 7) << 4))) = v;
    }
    stageB512(lwsT, Wn1T, 32, 0, tid);     // Wn1 k-half 0 (h)
    __syncthreads();

    floatx4 acc1 = (floatx4)0.f;
    gemm16(Xn, lwsT, acc1, 0, wid, quad, c, swz);     // GEMM1a: h-half
    __syncthreads();
    stageB512(lwsT, Wn1T, 32, 16, tid);    // Wn1 k-half 1 (m_aggr)
    __syncthreads();
    gemm16(Xn, lwsT, acc1, 128, wid, quad, c, swz);   // GEMM1b: m-half (accumulate)
    __syncthreads();                        // Xn[128..] reads done before S overwrite

    {
        int f = wid * 16 + c;
        float b1v = bn1[f];
#pragma unroll
        for (int r = 0; r < 4; r++) {
            int q = quad * 4 + r;
            *(short*)((char*)Xn + ((q * 512 + (128 + f) * 2) ^ ((q & 7) << 4))) =
                f2bf(silu_f(acc1[r] + b1v));
        }
    }
    stageB512(lwsT, Wn2T, 16, 0, tid);
    __syncthreads();

    floatx4 acc2 = (floatx4)0.f;
    gemm16(Xn, lwsT, acc2, 128, wid, quad, c, swz);   // GEMM2: S · Wn2
    __syncthreads();                        // lwsT reads done before W1mid stage

    {
        int f = wid * 16 + c;
        float b2 = bn2[f];
#pragma unroll
        for (int r = 0; r < 4; r++) {
            int q = quad * 4 + r;
            int gq = q0 + q;
            float hv = hq[gq * HD + f] + acc2[r] + b2;
            hq[gq * HD + f] = hv;
            *(short*)((char*)Xn + ((q * 512 + f * 2) ^ ((q & 7) << 4))) = f2bf(hv);
        }
    }
    stageB512(lwsT, W1midT, 16, 0, tid);
    __syncthreads();

    floatx4 acc3 = (floatx4)0.f;
    gemm16(Xn, lwsT, acc3, 0, wid, quad, c, swz);     // GEMM3: h' · W1mid -> next Bq
    {
        int f = wid * 16 + c;
#pragma unroll
        for (int r = 0; r < 4; r++)
            Bq[(q0 + quad * 4 + r) * HD + f] = acc3[r];
    }
}

extern "C" void kernel_launch(void* const* d_in, const int* in_sizes, int n_in,
                              void* d_out, int out_size, void* d_ws, size_t ws_size,
                              hipStream_t stream) {
    float* out = (float*)d_out;
    int fill_blocks = (out_size + 255) / 256;

    static const int exp_sz[16] = { 49152, 524288, 1536, 131584, 512, 65536, 512, 384,
                                    3, 640, 5, 131072, 512, 65536, 512, 524288 };
    bool ok = (n_in == 16);
    for (int i = 0; ok && i < 16; i++) if (in_sizes[i] != exp_sz[i]) ok = false;
    if (!ok || ws_size < (size_t)40 * 1024 * 1024) {
        k_fillf<<<fill_blocks, 256, 0, stream>>>(out, 777.0f, out_size);
        return;
    }

    const float* qp    = (const float*)d_in[0];
    const float* codes = (const float*)d_in[1];
    const float* gridp = (const float*)d_in[2];
    const float* eW1   = (const float*)d_in[3];
    const float* eb1   = (const float*)d_in[4];
    const float* eW2   = (const float*)d_in[5];
    const float* eb2   = (const float*)d_in[6];
    const float* cW    = (const float*)d_in[7];
    const float* cb    = (const float*)d_in[8];
    const float* fcW   = (const float*)d_in[9];
    const float* fcb   = (const float*)d_in[10];
    const float* nW1   = (const float*)d_in[11];
    const float* nb1   = (const float*)d_in[12];
    const float* nW2   = (const float*)d_in[13];
    const float* nb2   = (const float*)d_in[14];
    const int*   erow  = (const int*)d_in[15];

    float* ws = (float*)d_ws;
    float* x_q  = ws;  ws += N_PTS * 3;
    float* h_q  = ws;  ws += N_PTS * HD;
    float* hg_a = ws;  ws += N_GRID * HD;
    float* hg_b = ws;  ws += N_GRID * HD;
    float* Ag0  = ws;  ws += N_GRID * HD;
    float* Ag1  = ws;  ws += N_GRID * HD;
    float* Ag2  = ws;  ws += N_GRID * HD;
    float* Ag3  = ws;  ws += N_GRID * HD;
    float* Bqb  = ws;  ws += N_PTS * HD;
    short* wsT    = (short*)ws;        // 4 x 16384
    short* nW1T   = wsT + 65536;       // 3 x 32768
    short* nW2T   = nW1T + 98304;      // 3 x 16384
    short* W1midT = nW2T + 49152;      // 3 x 16384
    short* W1topT = W1midT + 49152;    // 4 x 16384
    float* Agb[4] = { Ag0, Ag1, Ag2, Ag3 };
    float* hgs[2] = { hg_a, hg_b };

    k_init<<<2048, 256, 0, stream>>>(qp, codes, x_q, hg_a, h_q, Bqb);
    k_prep<<<(4 * HD * HD + 255) / 256, 256, 0, stream>>>(eW2, wsT);
    k_prep2<<<(3 * 32768 + 6 * 16384 + 4 * 16384 + 255) / 256, 256, 0, stream>>>(
        nW1, nW2, eW1, nW1T, nW2T, W1midT, W1topT);

    // grid-node pipeline: all 4 layers up front (independent of edges)
    for (int L = 0; L < 4; L++) {
        int nl = (L < 3) ? L : 0;
        k_ga2<<<N_GRID / 64, 256, 0, stream>>>(
            hgs[L & 1], Agb[L], W1topT + L * 16384, eb1 + L * 128,
            nW1T + nl * 32768, nb1 + L * 128, nW2T + nl * 16384, nb2 + L * 128,
            (L < 3) ? 1 : 0, hgs[(L + 1) & 1]);
    }

    for (int i = 0; i < 4; i++) {
        const float* W1l = eW1 + i * 257 * 128;
        if (i < 3) {
            k_edge<1, false><<<EBLK, 512, 0, stream>>>(
                Agb[i], Bqb, x_q, W1l + 256 * 128, wsT + i * 16384, eb2 + i * 128,
                cW + i * 128, cb + i, erow, gridp, qp, out,
                nb1 + i * 128, nb2 + i * 128, nW1T + i * 32768, nW2T + i * 16384,
                W1midT + i * 16384, h_q);
        } else {
            k_edge<5, true><<<EBLK, 512, 0, stream>>>(
                Agb[3], Bqb, x_q, W1l + 256 * 128, wsT + i * 16384, eb2 + i * 128,
                fcW, fcb, erow, gridp, qp, out,
                nullptr, nullptr, nullptr, nullptr, nullptr, nullptr);
        }
    }
}